// Round 9
// baseline (1698.515 us; speedup 1.0000x reference)
//
#include <hip/hip_runtime.h>

typedef __bf16 bf16x8 __attribute__((ext_vector_type(8)));
typedef float f32x4 __attribute__((ext_vector_type(4)));

#define MFMA(a,b,c) __builtin_amdgcn_mfma_f32_16x16x32_bf16((a),(b),(c),0,0,0)

__device__ __forceinline__ float rcp_(float x){ return __builtin_amdgcn_rcpf(x); }

#define L2E 1.4426950408889634f

// tbl element-offset map (bf16 elements unless noted):
//   G1  [0,     16384): frag f=(g*4+hs)*2+s, el = f*512 + lane*8 + e   (prev, xL2E, g2 x2)
//   G2  [16384, 32768): same frag layout                               (up,   xL2E, g2 x2)
//   cP  [32768, 36864): f=hs*2+s, el = 32768 + f*512 + lane*8 + e      (Wh2 prev half)
//   cU  [36864, 40960):                                                 (Wh2 up half)
//   fc  [40960, 41984): f=s, el = 40960 + s*512 + lane*8 + e           (Wfc[0]-Wfc[1])
//   floats at byte 83968: base[lane*16+j] then dvec at +1024 floats
#define TBL_FLOAT_BYTE 83968

__global__ __launch_bounds__(256) void prep_kernel(
    const float* __restrict__ Wh,  const float* __restrict__ Wh2,
    const float* __restrict__ Whh, const float* __restrict__ Wfc,
    const float* __restrict__ Wih, const float* __restrict__ bih,
    const float* __restrict__ bhh,
    char* __restrict__ tblc)
{
  const int idx = blockIdx.x*256 + threadIdx.x;
  __bf16* tb = (__bf16*)tblc;
  float*  fb = (float*)(tblc + TBL_FLOAT_BYTE);
  if (idx < 32768){                       // G1/G2 folds
    const int e = idx & 7, lane = (idx >> 3) & 63, f = (idx >> 9) & 31, half = idx >> 14;
    const int s = f & 1, hs = (f >> 1) & 3, g = f >> 3;
    const int l16 = lane & 15, g4 = lane >> 4;
    const int n = g*64 + hs*16 + l16;
    const int k = s*32 + g4*8 + e;
    float acc = 0.f;
    for (int j=0; j<64; ++j) acc += Whh[n*64 + j] * Wh[j*128 + half*64 + k];
    const float sc = L2E * ((g == 2) ? 2.f : 1.f);
    tb[half*16384 + (f*64 + lane)*8 + e] = (__bf16)(acc * sc);
  } else if (idx < 40960){                // cP/cU
    const int j = idx - 32768;
    const int e = j & 7, lane = (j >> 3) & 63, f = (j >> 9) & 7, half = j >> 12;
    const int s = f & 1, hs = f >> 1;
    const int l16 = lane & 15, g4 = lane >> 4;
    const int n = hs*16 + l16;
    const int k = s*32 + g4*8 + e;
    tb[32768 + half*4096 + (f*64 + lane)*8 + e] = (__bf16)Wh2[n*128 + half*64 + k];
  } else if (idx < 41984){                // fc diff
    const int j = idx - 40960;
    const int e = j & 7, lane = (j >> 3) & 63, s = j >> 9;
    const int g4 = lane >> 4;
    const int k = s*32 + g4*8 + e;
    tb[40960 + (s*64 + lane)*8 + e] = (__bf16)(Wfc[k] - Wfc[64 + k]);
  } else if (idx < 44032){                // base/dvec
    const int j = idx - 41984;
    const int kind = j >> 10, q = j & 1023;
    const int lane = q >> 4, gh = q & 15;
    const int g = gh >> 2, hs = gh & 3, l16 = lane & 15;
    const int n = g*64 + hs*16 + l16;
    const float sc = L2E * ((g == 2) ? 2.f : 1.f);
    const float v = kind ? sc*(Wih[2*n] - Wih[2*n+1])
                         : sc*(bih[n] + bhh[n] + Wih[2*n+1]);
    fb[kind*1024 + q] = v;
  }
}

// ---------------- main: 512 blocks x 64 threads (ONE wave, 8 samples) -------
// The wave carries the full hidden state for its 8 samples through all 256
// cells: NO __syncthreads anywhere -- cell-to-cell hand-off is a same-wave
// LDS roundtrip ordered by lgkmcnt. M-tile rows 8..15 duplicate 0..7.
// State s_h/s_c: [col16][samp8][hid64] bf16, swizzle hid ^ (samp*8) ->
// conflict-free A-frag ds_read_b128. G1/cP/cU/fc B-frags live in VGPRs;
// G2 (up-weights, 32KB) streams from LDS off the critical chain. Epilogue:
// 8 els/lane via static-index selects. Softmax deferred to end phase.
// LDS ~78KB -> 2 independent blocks/CU.
__global__ __launch_bounds__(64,1) void lstm2d_kernel(
    const float* __restrict__ x,   const float* __restrict__ Wx,
    const float* __restrict__ bfc,
    const char* __restrict__ tblc,
    float* __restrict__ out)
{
  __shared__ __align__(16) __bf16 s_h[16*512];    // 16 KB  [col][samp][hid] swz
  __shared__ __align__(16) __bf16 s_c[16*512];    // 16 KB
  __shared__ __align__(16) __bf16 s_g2[16384];    // 32 KB
  __shared__ __align__(16) __bf16 s_xh[256*8];    // 4 KB   [slot][samp]
  __shared__ __align__(16) float  s_d[256*8];     // 8 KB   [slot][samp]
  __shared__ unsigned int s_msk[64];              // [samp][word]

  const int lane = threadIdx.x;        // 0..63
  const int l16  = lane & 15;
  const int g4   = lane >> 4;
  const int samp_a = l16 & 7;
  const bool lo2 = (g4 < 2);
  const int gsel = g4 & 1;

  const __bf16* tb = (const __bf16*)tblc;
  const float*  fbt = (const float*)(tblc + TBL_FLOAT_BYTE);

  // ---- weights to VGPR ----
  bf16x8 G1f[4][4][2], cPf[4][2], cUf[4][2], fcf[2];
  #pragma unroll
  for (int g=0; g<4; ++g)
    #pragma unroll
    for (int hs=0; hs<4; ++hs)
      #pragma unroll
      for (int s=0; s<2; ++s)
        G1f[g][hs][s] = *(const bf16x8*)(tb + (((g*4+hs)*2+s)*64 + lane)*8);
  #pragma unroll
  for (int hs=0; hs<4; ++hs)
    #pragma unroll
    for (int s=0; s<2; ++s){
      cPf[hs][s] = *(const bf16x8*)(tb + 32768 + ((hs*2+s)*64 + lane)*8);
      cUf[hs][s] = *(const bf16x8*)(tb + 36864 + ((hs*2+s)*64 + lane)*8);
    }
  #pragma unroll
  for (int s=0; s<2; ++s)
    fcf[s] = *(const bf16x8*)(tb + 40960 + (s*64 + lane)*8);
  float base_[16], dvec_[16];
  #pragma unroll
  for (int j=0; j<16; ++j){
    base_[j] = fbt[lane*16 + j];
    dvec_[j] = fbt[1024 + lane*16 + j];
  }

  // ---- G2 -> LDS; zero state ----
  #pragma unroll
  for (int f=0; f<32; ++f){
    bf16x8 v = *(const bf16x8*)(tb + 16384 + (f*64 + lane)*8);
    *(bf16x8*)(s_g2 + f*512 + lane*8) = v;
  }
  {
    bf16x8 z8 = {};
    #pragma unroll
    for (int j=0; j<16; ++j){
      *(bf16x8*)(s_h + j*512 + lane*8) = z8;
      *(bf16x8*)(s_c + j*512 + lane*8) = z8;
    }
  }

  // ---- xh + mask ----
  const float wx0 = Wx[0], wx1 = Wx[1];
  const float* xg = x + blockIdx.x * 2048;
  for (int j=0; j<32; ++j){
    const int idx = j*64 + lane;
    const int row = idx & 7, slot = idx >> 3;
    const int i = slot >> 4, t = slot & 15;
    const int c   = (i & 1) ? 15 - t : t;
    const int cpc = (i & 1) ? c + 1 : c - 1;
    const float xp = (t > 0) ? xg[row*256 + i*16 + cpc] : 0.f;
    const float xu = (i > 0) ? xg[row*256 + (i-1)*16 + c] : 0.f;
    s_xh[slot*8 + row] = (__bf16)((xp*wx0 + xu*wx1 + 1.f) * 0.5f);
  }
  {
    const int row = lane >> 3, wd = lane & 7;
    unsigned int m = 0;
    for (int b=0; b<32; ++b){
      const int slot = wd*32 + b, i = slot >> 4, t = slot & 15;
      const int c = (i & 1) ? 15 - t : t;
      if (xg[row*256 + i*16 + c] > 0.f) m |= (1u << b);
    }
    s_msk[lane] = m;
  }

  const float bd = bfc[0] - bfc[1];
  const float C2 = -2.f*L2E;

  // A-frag read offsets (elements): samp*64 + (k-byte-chunk ^ samp-swizzle)
  const int offA0 = samp_a*64 + ((     g4*8) ^ (samp_a*8));
  const int offA1 = samp_a*64 + ((32 + g4*8) ^ (samp_a*8));
  // epilogue write offsets: 2 hid-groups x 4 samples, all static-indexed
  int stO[2][4];
  #pragma unroll
  for (int e=0; e<2; ++e){
    const int hsE = lo2 ? e : e + 2;
    const int hid = hsE*16 + l16;
    #pragma unroll
    for (int r=0; r<4; ++r){
      const int sp = gsel*4 + r;
      stO[e][r] = sp*64 + (hid ^ (sp*8));
    }
  }

  for (int i=0; i<16; ++i){
    const int dir = i & 1;
    for (int t=0; t<16; ++t){
      const int c    = dir ? 15 - t : t;
      const int slot = i*16 + t;
      const int cb   = c << 9;

      // gate-accumulator init from xh
      const __bf16* xp = s_xh + slot*8 + gsel*4;
      const float xh0 = (float)xp[0], xh1 = (float)xp[1];
      const float xh2 = (float)xp[2], xh3 = (float)xp[3];
      f32x4 accG[4][4];
      #pragma unroll
      for (int g=0; g<4; ++g)
        #pragma unroll
        for (int hs=0; hs<4; ++hs){
          const float b = base_[g*4+hs], d = dvec_[g*4+hs];
          accG[g][hs][0] = b + xh0*d; accG[g][hs][1] = b + xh1*d;
          accG[g][hs][2] = b + xh2*d; accG[g][hs][3] = b + xh3*d;
        }

      // up-state frags (col c, previous row's values -- ready immediately)
      bf16x8 uh0 = *(const bf16x8*)(s_h + cb + offA0);
      bf16x8 uh1 = *(const bf16x8*)(s_h + cb + offA1);
      bf16x8 uc0 = *(const bf16x8*)(s_c + cb + offA0);
      bf16x8 uc1 = *(const bf16x8*)(s_c + cb + offA1);

      // up GEMM (B streamed from LDS)
      #pragma unroll
      for (int g=0; g<4; ++g)
        #pragma unroll
        for (int hs=0; hs<4; ++hs){
          bf16x8 b0 = *(const bf16x8*)(s_g2 + ((g*4+hs)*2    )*512 + lane*8);
          bf16x8 b1 = *(const bf16x8*)(s_g2 + ((g*4+hs)*2 + 1)*512 + lane*8);
          accG[g][hs] = MFMA(uh0, b0, accG[g][hs]);
          accG[g][hs] = MFMA(uh1, b1, accG[g][hs]);
        }
      f32x4 accC[4];
      #pragma unroll
      for (int hs=0; hs<4; ++hs){
        f32x4 z = {0.f,0.f,0.f,0.f};
        accC[hs] = MFMA(uc0, cUf[hs][0], z);
        accC[hs] = MFMA(uc1, cUf[hs][1], accC[hs]);
      }

      // prev-state frags + GEMM (critical chain), fc for d(slot-1)
      if (t > 0){
        const int pb = (dir ? c + 1 : c - 1) << 9;
        bf16x8 ah0 = *(const bf16x8*)(s_h + pb + offA0);
        bf16x8 ah1 = *(const bf16x8*)(s_h + pb + offA1);
        bf16x8 ac0 = *(const bf16x8*)(s_c + pb + offA0);
        bf16x8 ac1 = *(const bf16x8*)(s_c + pb + offA1);
        #pragma unroll
        for (int g=0; g<4; ++g)
          #pragma unroll
          for (int hs=0; hs<4; ++hs){
            accG[g][hs] = MFMA(ah0, G1f[g][hs][0], accG[g][hs]);
            accG[g][hs] = MFMA(ah1, G1f[g][hs][1], accG[g][hs]);
          }
        #pragma unroll
        for (int hs=0; hs<4; ++hs){
          accC[hs] = MFMA(ac0, cPf[hs][0], accC[hs]);
          accC[hs] = MFMA(ac1, cPf[hs][1], accC[hs]);
        }
        f32x4 accF = {bd,bd,bd,bd};
        accF = MFMA(ah0, fcf[0], accF);
        accF = MFMA(ah1, fcf[1], accF);
        if (l16 == 0 && lo2){
          #pragma unroll
          for (int r=0;r<4;++r) s_d[(slot-1)*8 + gsel*4 + r] = accF[r];
        }
      } else if (i > 0){
        // h(slot-1) == up-state at col c (prev row ended here)
        f32x4 accF = {bd,bd,bd,bd};
        accF = MFMA(uh0, fcf[0], accF);
        accF = MFMA(uh1, fcf[1], accF);
        if (l16 == 0 && lo2){
          #pragma unroll
          for (int r=0;r<4;++r) s_d[(slot-1)*8 + gsel*4 + r] = accF[r];
        }
      }

      // epilogue: 8 els/lane (2 hid-groups x 4 samples), static selects
      #pragma unroll
      for (int e=0; e<2; ++e){
        const f32x4 vI = lo2 ? accG[0][e] : accG[0][e+2];
        const f32x4 vF = lo2 ? accG[1][e] : accG[1][e+2];
        const f32x4 vG = lo2 ? accG[2][e] : accG[2][e+2];
        const f32x4 vO = lo2 ? accG[3][e] : accG[3][e+2];
        const f32x4 vC = lo2 ? accC[e]    : accC[e+2];
        #pragma unroll
        for (int r=0; r<4; ++r){
          const float si = rcp_(1.f + exp2f(-vI[r]));
          const float sf = rcp_(1.f + exp2f(-vF[r]));
          const float tg = 2.f * rcp_(1.f + exp2f(-vG[r])) - 1.f;
          const float cn = sf*vC[r] + si*tg;
          const float so = rcp_(1.f + exp2f(-vO[r]));
          const float tc = 2.f * rcp_(1.f + exp2f(C2*cn)) - 1.f;
          const float hn = so * tc;
          s_h[cb + stO[e][r]] = (__bf16)hn;
          s_c[cb + stO[e][r]] = (__bf16)cn;
        }
      }
    }
  }

  // d(255): slot 255 ends at column 0
  {
    bf16x8 fh0 = *(const bf16x8*)(s_h + offA0);
    bf16x8 fh1 = *(const bf16x8*)(s_h + offA1);
    f32x4 accF = {bd,bd,bd,bd};
    accF = MFMA(fh0, fcf[0], accF);
    accF = MFMA(fh1, fcf[1], accF);
    if (l16 == 0 && lo2){
      #pragma unroll
      for (int r=0;r<4;++r) s_d[255*8 + gsel*4 + r] = accF[r];
    }
  }

  // ---- end phase: 2048 log-softmax terms, wave-parallel ----
  {
    const int samp = lane & 7, sgrp = lane >> 3;
    float lpp = 0.f;
    for (int j=0; j<32; ++j){
      const int slot = sgrp*32 + j;
      const float d = s_d[slot*8 + samp];
      const int msk = (s_msk[samp*8 + (slot >> 5)] >> (slot & 31)) & 1;
      const float zz = msk ? -d : d;
      lpp -= __logf(1.f + __expf(zz));
    }
    lpp += __shfl_xor(lpp, 8);
    lpp += __shfl_xor(lpp, 16);
    lpp += __shfl_xor(lpp, 32);
    if (lane < 8){
      const int row = lane;
      float lp = lpp;
      int aa = 0;
      #pragma unroll
      for (int wd=0; wd<8; ++wd) aa += __popc(s_msk[row*8 + wd]);
      const int m255 = (s_msk[row*8 + 7] >> 31) & 1;
      if (aa == 1 && m255){
        const float d = s_d[255*8 + row];
        lp += __logf(1.f + __expf(-d));   // remove contrib (factor = 1 - mask)
      }
      out[blockIdx.x*8 + row] = lp;
    }
  }
}

extern "C" void kernel_launch(void* const* d_in, const int* in_sizes, int n_in,
                              void* d_out, int out_size, void* d_ws, size_t ws_size,
                              hipStream_t stream) {
  const float* x   = (const float*)d_in[0];
  const float* Wx  = (const float*)d_in[1];
  const float* Wh  = (const float*)d_in[2];
  const float* Wh2 = (const float*)d_in[3];
  const float* Wih = (const float*)d_in[4];
  const float* Whh = (const float*)d_in[5];
  const float* bih = (const float*)d_in[6];
  const float* bhh = (const float*)d_in[7];
  const float* Wfc = (const float*)d_in[8];
  const float* bfc = (const float*)d_in[9];
  float* out = (float*)d_out;
  char* tbl = (char*)d_ws;   // 92160 B

  prep_kernel<<<dim3(172), dim3(256), 0, stream>>>(Wh, Wh2, Whh, Wfc, Wih, bih, bhh, tbl);
  lstm2d_kernel<<<dim3(512), dim3(64), 0, stream>>>(x, Wx, bfc, tbl, out);
}

// Round 10
// 279.965 us; speedup vs baseline: 6.0669x; 6.0669x over previous
//
#include <hip/hip_runtime.h>

typedef __bf16 bf16x8 __attribute__((ext_vector_type(8)));
typedef float f32x4 __attribute__((ext_vector_type(4)));

#define MFMA(a,b,c) __builtin_amdgcn_mfma_f32_16x16x32_bf16((a),(b),(c),0,0,0)

__device__ __forceinline__ float rcp_(float x){ return __builtin_amdgcn_rcpf(x); }

#define L2E 1.4426950408889634f

// ---------------- prep: fold Whh@Wh_p / Whh@Wh_u, build bf16 B-frag table ----
// Per main-kernel tid (0..255): 22 frags x 8 bf16 = 176 elements.
//   f 0..7  : G1[g][s] = L2E*(Whh @ Wh_p)[n][k]   (x2 extra for g==2)
//   f 8..15 : G2[g][s] = L2E*(Whh @ Wh_u)[n][k]
//   f 16..19: bc[s]  = Wh2[n][k]  (K=128 = [prev|up], unscaled)
//   f 20..21: fc[s]  = Wfc[0][k] - Wfc[1][k]  (broadcast over n, unscaled)
__global__ __launch_bounds__(256) void prep_kernel(
    const float* __restrict__ Wh,  const float* __restrict__ Wh2,
    const float* __restrict__ Whh, const float* __restrict__ Wfc,
    __bf16* __restrict__ tbl)
{
  const int idx = blockIdx.x*256 + threadIdx.x;
  if (idx >= 256*176) return;
  const int e = idx & 7, f = (idx >> 3) % 22, t = idx / 176;
  const int w = t >> 6, lane = t & 63, l16 = lane & 15, g8 = (lane >> 4) * 8;
  float val;
  if (f < 16){
    const int g = (f >> 1) & 3, s = f & 1, half = f >> 3;
    const int n = g*64 + w*16 + l16;
    const int k = s*32 + g8 + e;
    const float* whcol = Wh + half*64 + k;        // Wh[j][half*64+k], stride 128
    float acc = 0.f;
    for (int j=0; j<64; ++j) acc += Whh[n*64 + j] * whcol[j*128];
    val = acc * ((g == 2) ? 2.f*L2E : L2E);
  } else if (f < 20){
    const int s = f - 16;
    const int n = w*16 + l16;
    const int k = s*32 + g8 + e;
    val = Wh2[n*128 + k];
  } else {
    const int s = f - 20;
    const int k = s*32 + g8 + e;
    val = Wfc[k] - Wfc[64 + k];
  }
  tbl[t*176 + f*8 + e] = (__bf16)val;
}

// ---------------- main: 512 blocks x 256 threads (4 waves, 8 samples) -------
// Block owns 8 batch rows (M-tile rows 8..15 duplicate 0..7). LDS ~48.4 KB ->
// 2 INDEPENDENT blocks/CU (8 waves/CU, 2/SIMD) whose stalls interleave.
// Wave w owns hidden cols [16w,16w+16) of all 4 gates + c_inter; VGPR ~104
// natural (no launch-bound forcing). One barrier/cell. VALU diet vs R7:
// (1) epilogue runs on ALL 64 lanes, 2 els each, via cndmask reg-half select
//     (duplicate acc halves carry the same samples); (2) gate weights and
//     biases pre-scaled by log2e so sigmoids/tanh use raw v_exp (exp2f).
// Softmax deferred: rotating wave ((slot-1)&3) parks d in s_d; parallel end
// phase does all log1p + popcount aa + rec fix.
__global__ __launch_bounds__(256,1) void lstm2d_kernel(
    const float* __restrict__ x,   const float* __restrict__ Wx,
    const float* __restrict__ Wih,
    const float* __restrict__ bih, const float* __restrict__ bhh,
    const float* __restrict__ bfc,
    const __bf16* __restrict__ tbl,
    float* __restrict__ out)
{
  __shared__ __align__(16) __bf16 s_h[16*8*64];    // [col][row][hid] 16 KB
  __shared__ __align__(16) __bf16 s_c[16*8*64];    // 16 KB
  __shared__ __align__(16) float  s_xh[256*8];     // [slot][row] 8 KB
  __shared__ __align__(16) float  s_d[256*8];      // [slot][row] 8 KB
  __shared__ unsigned int s_msk[8*8];              // [row][word] 256 B
  __shared__ float s_red[32];                      // [wave][row] 128 B

  const int tid  = threadIdx.x;
  const int w    = tid >> 6;
  const int lane = tid & 63;
  const int l16  = lane & 15;
  const int g4   = lane >> 4;
  const int g8   = g4 * 8;
  const int rl   = l16 & 7;           // batch row for A-reads (dup across l16>=8)
  const bool vld = (g4 < 2);          // lanes holding non-duplicate acc rows
  const bool sel = (g4 >= 2);         // epilogue: which reg-half this lane owns

  const float wx0 = Wx[0], wx1 = Wx[1];

  // zero state
  unsigned int* zh = (unsigned int*)s_h;
  unsigned int* zc = (unsigned int*)s_c;
  #pragma unroll
  for (int it=0; it<16; ++it){ zh[tid + it*256] = 0u; zc[tid + it*256] = 0u; }

  // xh precompute: 2048 entries
  const float* xg = x + blockIdx.x * 2048;
  #pragma unroll
  for (int k=0; k<8; ++k){
    const int idx = tid + k*256;
    const int row = idx & 7, slot = idx >> 3;
    const int i = slot >> 4, t = slot & 15;
    const int c   = (i & 1) ? 15 - t : t;
    const int cpc = (i & 1) ? c + 1 : c - 1;
    const float xp = (t > 0) ? xg[row*256 + i*16 + cpc] : 0.f;
    const float xu = (i > 0) ? xg[row*256 + (i-1)*16 + c] : 0.f;
    s_xh[slot*8 + row] = (xp*wx0 + xu*wx1 + 1.f) * 0.5f;
  }
  // mask bits: x>0 at each slot's own cell
  if (tid < 64){
    const int row = tid >> 3, wd = tid & 7;
    unsigned int m = 0;
    for (int b=0; b<32; ++b){
      const int slot = wd*32 + b, i = slot >> 4, t = slot & 15;
      const int c = (i & 1) ? 15 - t : t;
      if (xg[row*256 + i*16 + c] > 0.f) m |= (1u << b);
    }
    s_msk[row*8 + wd] = m;
  }

  // weight fragments from prep table (identical addresses across blocks -> L2)
  const __bf16* tb = tbl + tid*176;
  bf16x8 G1f[4][2], G2f[4][2], bcf[4], fcB[2];
  #pragma unroll
  for (int g=0; g<4; ++g)
    #pragma unroll
    for (int s=0; s<2; ++s){
      G1f[g][s] = *(const bf16x8*)(tb + (g*2+s)*8);
      G2f[g][s] = *(const bf16x8*)(tb + 64 + (g*2+s)*8);
    }
  #pragma unroll
  for (int s=0; s<4; ++s) bcf[s] = *(const bf16x8*)(tb + 128 + s*8);
  #pragma unroll
  for (int s=0; s<2; ++s) fcB[s] = *(const bf16x8*)(tb + 160 + s*8);

  const float bd = bfc[0] - bfc[1];
  float base_[4], dvec_[4];
  #pragma unroll
  for (int g=0; g<4; ++g){
    const int cg = g*64 + w*16 + l16;
    const float sc = (g == 2) ? 2.f*L2E : L2E;
    base_[g] = (bih[cg] + bhh[cg] + Wih[cg*2+1]) * sc;
    dvec_[g] = (Wih[cg*2+0] - Wih[cg*2+1]) * sc;
  }
  const int colw = w*16 + l16;

  // per-lane LDS offsets (elements); col stride = 512 els
  const int offA0 = rl*64 + ((     g8) ^ (rl << 3));
  const int offA1 = rl*64 + ((32 + g8) ^ (rl << 3));
  const int rsel  = sel ? 2 : 0;
  int stW[2];
  #pragma unroll
  for (int e=0; e<2; ++e){
    const int R = (g4 & 1)*4 + rsel + e;   // batch row (0..7) this lane owns
    stW[e] = R*64 + (colw ^ (R << 3));
  }
  const int xhOff = (g4 & 1) * 4;
  const float C2 = -2.f*L2E;

  __syncthreads();

  f32x4 accGu[4], aCu;

  for (int i=0; i<16; ++i){
    const int dir = i & 1;
    const int slot0 = i*16;

    // ---- row prologue: up-contribution for t=0 (+ wave3: d(slot0-1)) ----
    {
      const int b = (dir ? 15 : 0) << 9;
      bf16x8 ah0 = *(const bf16x8*)(s_h + b + offA0);
      bf16x8 ah1 = *(const bf16x8*)(s_h + b + offA1);
      bf16x8 qc0 = *(const bf16x8*)(s_c + b + offA0);
      bf16x8 qc1 = *(const bf16x8*)(s_c + b + offA1);
      const float4 xh4 = *(const float4*)(s_xh + slot0*8 + xhOff);
      #pragma unroll
      for (int g=0; g<4; ++g){
        accGu[g][0] = base_[g] + xh4.x * dvec_[g];
        accGu[g][1] = base_[g] + xh4.y * dvec_[g];
        accGu[g][2] = base_[g] + xh4.z * dvec_[g];
        accGu[g][3] = base_[g] + xh4.w * dvec_[g];
        accGu[g] = MFMA(ah0, G2f[g][0], accGu[g]);
        accGu[g] = MFMA(ah1, G2f[g][1], accGu[g]);
      }
      f32x4 z = {0.f,0.f,0.f,0.f};
      aCu = MFMA(qc0, bcf[2], z);
      aCu = MFMA(qc1, bcf[3], aCu);
      if (i > 0 && w == 3){                 // ((slot0-1)&3) == 3
        f32x4 fz = {bd,bd,bd,bd};
        fz = MFMA(ah0, fcB[0], fz);
        f32x4 aF = MFMA(ah1, fcB[1], fz);
        if (l16 == 0 && vld){
          #pragma unroll
          for (int r=0;r<4;++r) s_d[(slot0-1)*8 + (g4&1)*4 + r] = aF[r];
        }
      }
    }

    for (int t=0; t<16; ++t){
      const int c    = dir ? 15 - t : t;
      const int slot = slot0 + t;

      f32x4 accG[4], aC;
      if (t > 0){
        const int b = (dir ? c + 1 : c - 1) << 9;
        bf16x8 a0 = *(const bf16x8*)(s_h + b + offA0);
        bf16x8 a1 = *(const bf16x8*)(s_h + b + offA1);
        bf16x8 q0 = *(const bf16x8*)(s_c + b + offA0);
        bf16x8 q1 = *(const bf16x8*)(s_c + b + offA1);
        #pragma unroll
        for (int g=0; g<4; ++g){
          accG[g] = MFMA(a0, G1f[g][0], accGu[g]);
          accG[g] = MFMA(a1, G1f[g][1], accG[g]);
        }
        aC = MFMA(q0, bcf[0], aCu);
        aC = MFMA(q1, bcf[1], aC);
        if (w == ((t - 1) & 3)){
          f32x4 fz = {bd,bd,bd,bd};
          fz = MFMA(a0, fcB[0], fz);
          f32x4 aF = MFMA(a1, fcB[1], fz);
          if (l16 == 0 && vld){
            #pragma unroll
            for (int r=0;r<4;++r) s_d[(slot-1)*8 + (g4&1)*4 + r] = aF[r];
          }
        }
      } else {
        #pragma unroll
        for (int g=0; g<4; ++g) accG[g] = accGu[g];
        aC = aCu;
      }

      // prefetch next slot's up contribution (column c(t+1): prev-row data)
      if (t < 15){
        const int bu = (dir ? 14 - t : t + 1) << 9;
        bf16x8 au0 = *(const bf16x8*)(s_h + bu + offA0);
        bf16x8 au1 = *(const bf16x8*)(s_h + bu + offA1);
        bf16x8 cu0 = *(const bf16x8*)(s_c + bu + offA0);
        bf16x8 cu1 = *(const bf16x8*)(s_c + bu + offA1);
        const float4 xh4 = *(const float4*)(s_xh + (slot+1)*8 + xhOff);
        #pragma unroll
        for (int g=0; g<4; ++g){
          accGu[g][0] = base_[g] + xh4.x * dvec_[g];
          accGu[g][1] = base_[g] + xh4.y * dvec_[g];
          accGu[g][2] = base_[g] + xh4.z * dvec_[g];
          accGu[g][3] = base_[g] + xh4.w * dvec_[g];
          accGu[g] = MFMA(au0, G2f[g][0], accGu[g]);
          accGu[g] = MFMA(au1, G2f[g][1], accGu[g]);
        }
        f32x4 z = {0.f,0.f,0.f,0.f};
        aCu = MFMA(cu0, bcf[2], z);
        aCu = MFMA(cu1, bcf[3], aCu);
      }

      // ---- epilogue: ALL lanes, 2 els each (reg-half select), exp2 forms ----
      {
        const int cb = c << 9;
        #pragma unroll
        for (int e=0; e<2; ++e){
          const float ig = sel ? accG[0][2+e] : accG[0][e];
          const float fg = sel ? accG[1][2+e] : accG[1][e];
          const float gg = sel ? accG[2][2+e] : accG[2][e];
          const float og = sel ? accG[3][2+e] : accG[3][e];
          const float cI = sel ? aC[2+e]      : aC[e];
          const float si = rcp_(1.f + exp2f(-ig));
          const float sf = rcp_(1.f + exp2f(-fg));
          const float tg = 2.f * rcp_(1.f + exp2f(-gg)) - 1.f;
          const float cn = sf*cI + si*tg;
          const float so = rcp_(1.f + exp2f(-og));
          const float tc = 2.f * rcp_(1.f + exp2f(C2*cn)) - 1.f;
          const float hn = so * tc;
          s_h[cb + stW[e]] = (__bf16)hn;
          s_c[cb + stW[e]] = (__bf16)cn;
        }
      }

      __syncthreads();
    }
  }

  // d(255): slot 255 ends at column 0
  if (w == 3){
    bf16x8 a0 = *(const bf16x8*)(s_h + offA0);
    bf16x8 a1 = *(const bf16x8*)(s_h + offA1);
    f32x4 fz = {bd,bd,bd,bd};
    fz = MFMA(a0, fcB[0], fz);
    f32x4 aF = MFMA(a1, fcB[1], fz);
    if (l16 == 0 && vld){
      #pragma unroll
      for (int r=0;r<4;++r) s_d[255*8 + (g4&1)*4 + r] = aF[r];
    }
  }
  __syncthreads();

  // ---------- end phase: all 2048 log-softmax terms in parallel ----------
  {
    const int row = lane & 7, grpw = lane >> 3;      // 8 grps per wave
    float lpp = 0.f;
    #pragma unroll
    for (int e=0; e<8; ++e){
      const int slot = (w*8 + grpw)*8 + e;
      const float d = s_d[slot*8 + row];
      const int msk = (s_msk[row*8 + (slot >> 5)] >> (slot & 31)) & 1;
      const float zz = msk ? -d : d;
      lpp -= __logf(1.f + __expf(zz));
    }
    lpp += __shfl_xor(lpp, 8);
    lpp += __shfl_xor(lpp, 16);
    lpp += __shfl_xor(lpp, 32);
    if (lane < 8) s_red[w*8 + lane] = lpp;
  }
  __syncthreads();
  if (tid < 8){
    const int row = tid;
    float lp = 0.f;
    #pragma unroll
    for (int ww=0; ww<4; ++ww) lp += s_red[ww*8 + row];
    int aa = 0;
    #pragma unroll
    for (int wd=0; wd<8; ++wd) aa += __popc(s_msk[row*8 + wd]);
    const int m255 = (s_msk[row*8 + 7] >> 31) & 1;
    if (aa == 1 && m255){
      const float d = s_d[255*8 + row];
      lp += __logf(1.f + __expf(-d));   // remove contrib (factor = 1 - mask)
    }
    out[blockIdx.x*8 + row] = lp;
  }
}

extern "C" void kernel_launch(void* const* d_in, const int* in_sizes, int n_in,
                              void* d_out, int out_size, void* d_ws, size_t ws_size,
                              hipStream_t stream) {
  const float* x   = (const float*)d_in[0];
  const float* Wx  = (const float*)d_in[1];
  const float* Wh  = (const float*)d_in[2];
  const float* Wh2 = (const float*)d_in[3];
  const float* Wih = (const float*)d_in[4];
  const float* Whh = (const float*)d_in[5];
  const float* bih = (const float*)d_in[6];
  const float* bhh = (const float*)d_in[7];
  const float* Wfc = (const float*)d_in[8];
  const float* bfc = (const float*)d_in[9];
  float* out = (float*)d_out;
  __bf16* tbl = (__bf16*)d_ws;   // 256*176*2 = 90112 B

  prep_kernel<<<dim3(176), dim3(256), 0, stream>>>(Wh, Wh2, Whh, Wfc, tbl);
  lstm2d_kernel<<<dim3(512), dim3(256), 0, stream>>>(
      x, Wx, Wih, bih, bhh, bfc, tbl, out);
}

// Round 11
// 249.132 us; speedup vs baseline: 6.8177x; 1.1238x over previous
//
#include <hip/hip_runtime.h>

typedef __bf16 bf16x8 __attribute__((ext_vector_type(8)));
typedef float f32x4 __attribute__((ext_vector_type(4)));

#define MFMA(a,b,c) __builtin_amdgcn_mfma_f32_16x16x32_bf16((a),(b),(c),0,0,0)

__device__ __forceinline__ float rcp_(float x){ return __builtin_amdgcn_rcpf(x); }

#define L2E 1.4426950408889634f

// ---------------- prep: fold Whh@Wh_p / Whh@Wh_u, build bf16 B-frag table ----
// Per main-kernel tid (0..255): 22 frags x 8 bf16 = 176 elements.
//   f 0..7  : G1[g][s] = L2E*(Whh @ Wh_p)[n][k]   (x2 extra for g==2)
//   f 8..15 : G2[g][s] = L2E*(Whh @ Wh_u)[n][k]
//   f 16..19: bc[s]  = Wh2[n][k]  (K=128 = [prev|up], unscaled)
//   f 20..21: fc[s]  = Wfc[0][k] - Wfc[1][k] (broadcast over n, unscaled)
__global__ __launch_bounds__(256) void prep_kernel(
    const float* __restrict__ Wh,  const float* __restrict__ Wh2,
    const float* __restrict__ Whh, const float* __restrict__ Wfc,
    __bf16* __restrict__ tbl)
{
  const int idx = blockIdx.x*256 + threadIdx.x;
  if (idx >= 256*176) return;
  const int e = idx & 7, f = (idx >> 3) % 22, t = idx / 176;
  const int w = t >> 6, lane = t & 63, l16 = lane & 15, g8 = (lane >> 4) * 8;
  float val;
  if (f < 16){
    const int g = (f >> 1) & 3, s = f & 1, half = f >> 3;
    const int n = g*64 + w*16 + l16;
    const int k = s*32 + g8 + e;
    const float* whcol = Wh + half*64 + k;        // Wh[j][half*64+k], stride 128
    float acc = 0.f;
    for (int j=0; j<64; ++j) acc += Whh[n*64 + j] * whcol[j*128];
    val = acc * ((g == 2) ? 2.f*L2E : L2E);
  } else if (f < 20){
    const int s = f - 16;
    const int n = w*16 + l16;
    const int k = s*32 + g8 + e;
    val = Wh2[n*128 + k];
  } else {
    const int s = f - 20;
    const int k = s*32 + g8 + e;
    val = Wfc[k] - Wfc[64 + k];
  }
  tbl[t*176 + f*8 + e] = (__bf16)val;
}

// ---------------- main: 256 blocks x 256 threads (4 waves, 16 samples) ------
// R4's chip-optimal work layout (1 block/CU, 16 REAL samples, no duplication)
// with the transcendental diet: (1) softmax deferred -- rotating wave
// ((t-1)&3) parks the fc logit-diff d in s_d, one parallel end phase does all
// log1p; (2) gate weights/biases pre-scaled by log2e -> raw v_exp (exp2f);
// (3) merged-rcp epilogue: cn and hn computed with 2 rcp instead of 5 per
// element (same algebra, fewer quarter-rate trans ops). One barrier per cell.
__global__ __launch_bounds__(256,1) void lstm2d_kernel(
    const float* __restrict__ x,   const float* __restrict__ Wx,
    const float* __restrict__ Wih,
    const float* __restrict__ bih, const float* __restrict__ bhh,
    const float* __restrict__ bfc,
    const __bf16* __restrict__ tbl,
    float* __restrict__ out)
{
  __shared__ __align__(16) __bf16 s_h[16*16*64];   // [col][row][hid] 32 KB
  __shared__ __align__(16) __bf16 s_c[16*16*64];   // 32 KB
  __shared__ __align__(16) float  s_xh[256*16];    // [slot][row] 16 KB
  __shared__ __align__(16) float  s_d[256*16];     // [slot][row] 16 KB
  __shared__ unsigned int s_msk[16*8];             // [row][word] 512 B
  __shared__ float s_red[256];                     // [grp][row] 1 KB

  const int tid  = threadIdx.x;
  const int w    = tid >> 6;
  const int lane = tid & 63;
  const int l16  = lane & 15;
  const int g4   = lane >> 4;
  const int g8   = g4 * 8;

  const float wx0 = Wx[0], wx1 = Wx[1];

  // zero state
  unsigned int* zh = (unsigned int*)s_h;
  unsigned int* zc = (unsigned int*)s_c;
  #pragma unroll
  for (int it=0; it<32; ++it){ zh[tid + it*256] = 0u; zc[tid + it*256] = 0u; }

  // xh precompute: 4096 entries
  const float* xg = x + blockIdx.x * 4096;
  #pragma unroll
  for (int k=0; k<16; ++k){
    const int idx = tid + k*256;
    const int row = idx & 15, slot = idx >> 4;
    const int i = slot >> 4, t = slot & 15;
    const int c   = (i & 1) ? 15 - t : t;
    const int cpc = (i & 1) ? c + 1 : c - 1;
    const float xp = (t > 0) ? xg[row*256 + i*16 + cpc] : 0.f;
    const float xu = (i > 0) ? xg[row*256 + (i-1)*16 + c] : 0.f;
    s_xh[slot*16 + row] = (xp*wx0 + xu*wx1 + 1.f) * 0.5f;
  }
  // mask bits: x>0 at each slot's own cell
  if (tid < 128){
    const int row = tid >> 3, wd = tid & 7;
    unsigned int m = 0;
    for (int b=0; b<32; ++b){
      const int slot = wd*32 + b, i = slot >> 4, t = slot & 15;
      const int c = (i & 1) ? 15 - t : t;
      if (xg[row*256 + i*16 + c] > 0.f) m |= (1u << b);
    }
    s_msk[row*8 + wd] = m;
  }

  // weight fragments from prep table (identical addresses across blocks -> L2)
  const __bf16* tb = tbl + tid*176;
  bf16x8 G1f[4][2], G2f[4][2], bcf[4], fcB[2];
  #pragma unroll
  for (int g=0; g<4; ++g)
    #pragma unroll
    for (int s=0; s<2; ++s){
      G1f[g][s] = *(const bf16x8*)(tb + (g*2+s)*8);
      G2f[g][s] = *(const bf16x8*)(tb + 64 + (g*2+s)*8);
    }
  #pragma unroll
  for (int s=0; s<4; ++s) bcf[s] = *(const bf16x8*)(tb + 128 + s*8);
  #pragma unroll
  for (int s=0; s<2; ++s) fcB[s] = *(const bf16x8*)(tb + 160 + s*8);

  const float bd = bfc[0] - bfc[1];
  float base_[4], dvec_[4];
  #pragma unroll
  for (int g=0; g<4; ++g){
    const int cg = g*64 + w*16 + l16;
    const float sc = (g == 2) ? 2.f*L2E : L2E;
    base_[g] = (bih[cg] + bhh[cg] + Wih[cg*2+1]) * sc;
    dvec_[g] = (Wih[cg*2+0] - Wih[cg*2+1]) * sc;
  }
  const int colw = w*16 + l16;

  // per-lane LDS offsets (elements); col stride = 1024 els
  const int offA0 = l16*64 + ((     g8) ^ ((l16 & 7) << 3));
  const int offA1 = l16*64 + ((32 + g8) ^ ((l16 & 7) << 3));
  int stW[4];
  #pragma unroll
  for (int r=0;r<4;++r){
    const int row = g4*4 + r;
    stW[r] = row*64 + (colw ^ ((row & 7) << 3));
  }
  const float C2 = -2.f*L2E;

  __syncthreads();

  f32x4 accGu[4], aCu;

  for (int i=0; i<16; ++i){
    const int dir = i & 1;
    const int slot0 = i*16;

    // ---- row prologue: up-contribution for t=0 (+ wave3: d(slot0-1)) ----
    {
      const int b = (dir ? 15 : 0) << 10;
      bf16x8 ah0 = *(const bf16x8*)(s_h + b + offA0);
      bf16x8 ah1 = *(const bf16x8*)(s_h + b + offA1);
      bf16x8 qc0 = *(const bf16x8*)(s_c + b + offA0);
      bf16x8 qc1 = *(const bf16x8*)(s_c + b + offA1);
      const float4 xh4 = *(const float4*)(s_xh + slot0*16 + g4*4);
      #pragma unroll
      for (int g=0; g<4; ++g){
        accGu[g][0] = base_[g] + xh4.x * dvec_[g];
        accGu[g][1] = base_[g] + xh4.y * dvec_[g];
        accGu[g][2] = base_[g] + xh4.z * dvec_[g];
        accGu[g][3] = base_[g] + xh4.w * dvec_[g];
        accGu[g] = MFMA(ah0, G2f[g][0], accGu[g]);
        accGu[g] = MFMA(ah1, G2f[g][1], accGu[g]);
      }
      f32x4 z = {0.f,0.f,0.f,0.f};
      aCu = MFMA(qc0, bcf[2], z);
      aCu = MFMA(qc1, bcf[3], aCu);
      if (i > 0 && w == 3){                 // ((slot0-1)&3) == 3
        f32x4 fz = {bd,bd,bd,bd};
        fz = MFMA(ah0, fcB[0], fz);
        f32x4 aF = MFMA(ah1, fcB[1], fz);
        if (l16 == 0){
          #pragma unroll
          for (int r=0;r<4;++r) s_d[(slot0-1)*16 + g4*4 + r] = aF[r];
        }
      }
    }

    for (int t=0; t<16; ++t){
      const int c    = dir ? 15 - t : t;
      const int slot = slot0 + t;

      f32x4 accG[4], aC;
      if (t > 0){
        const int b = (dir ? c + 1 : c - 1) << 10;
        bf16x8 a0 = *(const bf16x8*)(s_h + b + offA0);
        bf16x8 a1 = *(const bf16x8*)(s_h + b + offA1);
        bf16x8 q0 = *(const bf16x8*)(s_c + b + offA0);
        bf16x8 q1 = *(const bf16x8*)(s_c + b + offA1);
        #pragma unroll
        for (int g=0; g<4; ++g){
          accG[g] = MFMA(a0, G1f[g][0], accGu[g]);
          accG[g] = MFMA(a1, G1f[g][1], accG[g]);
        }
        aC = MFMA(q0, bcf[0], aCu);
        aC = MFMA(q1, bcf[1], aC);
        if (w == ((t - 1) & 3)){
          f32x4 fz = {bd,bd,bd,bd};
          fz = MFMA(a0, fcB[0], fz);
          f32x4 aF = MFMA(a1, fcB[1], fz);
          if (l16 == 0){
            #pragma unroll
            for (int r=0;r<4;++r) s_d[(slot-1)*16 + g4*4 + r] = aF[r];
          }
        }
      } else {
        #pragma unroll
        for (int g=0; g<4; ++g) accG[g] = accGu[g];
        aC = aCu;
      }

      // prefetch next slot's up contribution (column c(t+1): prev-row data)
      if (t < 15){
        const int bu = (dir ? 14 - t : t + 1) << 10;
        bf16x8 au0 = *(const bf16x8*)(s_h + bu + offA0);
        bf16x8 au1 = *(const bf16x8*)(s_h + bu + offA1);
        bf16x8 cu0 = *(const bf16x8*)(s_c + bu + offA0);
        bf16x8 cu1 = *(const bf16x8*)(s_c + bu + offA1);
        const float4 xh4 = *(const float4*)(s_xh + (slot+1)*16 + g4*4);
        #pragma unroll
        for (int g=0; g<4; ++g){
          accGu[g][0] = base_[g] + xh4.x * dvec_[g];
          accGu[g][1] = base_[g] + xh4.y * dvec_[g];
          accGu[g][2] = base_[g] + xh4.z * dvec_[g];
          accGu[g][3] = base_[g] + xh4.w * dvec_[g];
          accGu[g] = MFMA(au0, G2f[g][0], accGu[g]);
          accGu[g] = MFMA(au1, G2f[g][1], accGu[g]);
        }
        f32x4 z = {0.f,0.f,0.f,0.f};
        aCu = MFMA(cu0, bcf[2], z);
        aCu = MFMA(cu1, bcf[3], aCu);
      }

      // ---- epilogue: merged-rcp activations (7 trans/el instead of 10) ----
      // A=2^-i', F=2^-f', B=2^-g'' (g''=2*l2e*g), O=2^-o'  (primes: x*l2e)
      // cn = [cI*(1+A)(1+B) + (1-B)(1+F)] / [(1+F)(1+A)(1+B)]
      // hn = (1-E)/[(1+O)(1+E)],  E = 2^(-2*l2e*cn)
      {
        const int cb = c << 10;
        #pragma unroll
        for (int r=0;r<4;++r){
          const float A = exp2f(-accG[0][r]);
          const float F = exp2f(-accG[1][r]);
          const float B = exp2f(-accG[2][r]);
          const float O = exp2f(-accG[3][r]);
          const float a1 = 1.f + A, f1 = 1.f + F, b1 = 1.f + B, o1 = 1.f + O;
          const float pab = a1 * b1;
          const float num = fmaf(1.f - B, f1, aC[r] * pab);
          const float cn  = num * rcp_(pab * f1);
          const float E   = exp2f(C2 * cn);
          const float hn  = (1.f - E) * rcp_(o1 * (1.f + E));
          s_h[cb + stW[r]] = (__bf16)hn;
          s_c[cb + stW[r]] = (__bf16)cn;
        }
      }

      __syncthreads();
    }
  }

  // d(255): slot 255 ends at column 0
  if (w == 3){
    bf16x8 a0 = *(const bf16x8*)(s_h + offA0);
    bf16x8 a1 = *(const bf16x8*)(s_h + offA1);
    f32x4 fz = {bd,bd,bd,bd};
    fz = MFMA(a0, fcB[0], fz);
    f32x4 aF = MFMA(a1, fcB[1], fz);
    if (l16 == 0){
      #pragma unroll
      for (int r=0;r<4;++r) s_d[255*16 + g4*4 + r] = aF[r];
    }
  }
  __syncthreads();

  // ---------- end phase: all 4096 log-softmax terms in parallel ----------
  {
    const int row = tid & 15, grp = tid >> 4;   // 16 groups x 16 slots
    float lpp = 0.f;
    #pragma unroll
    for (int e=0; e<16; ++e){
      const int slot = grp*16 + e;
      const float d = s_d[slot*16 + row];
      const int msk = (s_msk[row*8 + (slot >> 5)] >> (slot & 31)) & 1;
      const float zz = msk ? -d : d;
      lpp -= __logf(1.f + __expf(zz));
    }
    s_red[grp*16 + row] = lpp;
  }
  __syncthreads();
  if (tid < 16){
    const int row = tid;
    float lp = 0.f;
    #pragma unroll
    for (int g=0; g<16; ++g) lp += s_red[g*16 + row];
    int aa = 0;
    #pragma unroll
    for (int wd=0; wd<8; ++wd) aa += __popc(s_msk[row*8 + wd]);
    const int m255 = (s_msk[row*8 + 7] >> 31) & 1;
    if (aa == 1 && m255){
      const float d = s_d[255*16 + row];
      lp += __logf(1.f + __expf(-d));   // remove contrib (factor = 1 - mask)
    }
    out[blockIdx.x*16 + row] = lp;
  }
}

extern "C" void kernel_launch(void* const* d_in, const int* in_sizes, int n_in,
                              void* d_out, int out_size, void* d_ws, size_t ws_size,
                              hipStream_t stream) {
  const float* x   = (const float*)d_in[0];
  const float* Wx  = (const float*)d_in[1];
  const float* Wh  = (const float*)d_in[2];
  const float* Wh2 = (const float*)d_in[3];
  const float* Wih = (const float*)d_in[4];
  const float* Whh = (const float*)d_in[5];
  const float* bih = (const float*)d_in[6];
  const float* bhh = (const float*)d_in[7];
  const float* Wfc = (const float*)d_in[8];
  const float* bfc = (const float*)d_in[9];
  float* out = (float*)d_out;
  __bf16* tbl = (__bf16*)d_ws;   // 256*176*2 = 90112 B

  prep_kernel<<<dim3(176), dim3(256), 0, stream>>>(Wh, Wh2, Whh, Wfc, tbl);
  lstm2d_kernel<<<dim3(256), dim3(256), 0, stream>>>(
      x, Wx, Wih, bih, bhh, bfc, tbl, out);
}

// Round 12
// 237.128 us; speedup vs baseline: 7.1628x; 1.0506x over previous
//
#include <hip/hip_runtime.h>

typedef __bf16 bf16x8 __attribute__((ext_vector_type(8)));
typedef float f32x4 __attribute__((ext_vector_type(4)));

#define MFMA(a,b,c) __builtin_amdgcn_mfma_f32_16x16x32_bf16((a),(b),(c),0,0,0)

__device__ __forceinline__ float rcp_(float x){ return __builtin_amdgcn_rcpf(x); }

#define L2E 1.4426950408889634f

// ---------------- prep: fold Whh@Wh_p / Whh@Wh_u, build bf16 B-frag table ----
// Per main-kernel tid (0..255): 22 frags x 8 bf16 = 176 elements.
//   f 0..7  : G1[g][s] = L2E*(Whh @ Wh_p)[n][k]   (x2 extra for g==2)
//   f 8..15 : G2[g][s] = L2E*(Whh @ Wh_u)[n][k]
//   f 16..19: bc[s]  = Wh2[n][k]  (K=128 = [prev|up], unscaled)
//   f 20..21: fc[s]  = Wfc[0][k] - Wfc[1][k] (broadcast over n, unscaled)
__global__ __launch_bounds__(256) void prep_kernel(
    const float* __restrict__ Wh,  const float* __restrict__ Wh2,
    const float* __restrict__ Whh, const float* __restrict__ Wfc,
    __bf16* __restrict__ tbl)
{
  const int idx = blockIdx.x*256 + threadIdx.x;
  if (idx >= 256*176) return;
  const int e = idx & 7, f = (idx >> 3) % 22, t = idx / 176;
  const int w = t >> 6, lane = t & 63, l16 = lane & 15, g8 = (lane >> 4) * 8;
  float val;
  if (f < 16){
    const int g = (f >> 1) & 3, s = f & 1, half = f >> 3;
    const int n = g*64 + w*16 + l16;
    const int k = s*32 + g8 + e;
    const float* whcol = Wh + half*64 + k;        // Wh[j][half*64+k], stride 128
    float acc = 0.f;
    for (int j=0; j<64; ++j) acc += Whh[n*64 + j] * whcol[j*128];
    val = acc * ((g == 2) ? 2.f*L2E : L2E);
  } else if (f < 20){
    const int s = f - 16;
    const int n = w*16 + l16;
    const int k = s*32 + g8 + e;
    val = Wh2[n*128 + k];
  } else {
    const int s = f - 20;
    const int k = s*32 + g8 + e;
    val = Wfc[k] - Wfc[64 + k];
  }
  tbl[t*176 + f*8 + e] = (__bf16)val;
}

// ---------------- main: 256 blocks x 256 threads (4 waves, 16 samples) ------
// R11 structure (1 block/CU, 16 real samples, deferred softmax, log2e
// prescale, merged-rcp epilogue) with a latency-oriented cell schedule:
// all 9 loads (prev state, next-slot up state, next xh) issue immediately
// after the barrier; the epilogue's trans block runs BEFORE the prefetch
// MFMAs so the up-read latency hides under phase-1 MFMA + trans issue; state
// writes precede the prefetch MFMAs so write completion hides under MFMA
// issue. t-loop unrolled 4x (VGPRs are free at 1 wave/SIMD).
__global__ __launch_bounds__(256,1) void lstm2d_kernel(
    const float* __restrict__ x,   const float* __restrict__ Wx,
    const float* __restrict__ Wih,
    const float* __restrict__ bih, const float* __restrict__ bhh,
    const float* __restrict__ bfc,
    const __bf16* __restrict__ tbl,
    float* __restrict__ out)
{
  __shared__ __align__(16) __bf16 s_h[16*16*64];   // [col][row][hid] 32 KB
  __shared__ __align__(16) __bf16 s_c[16*16*64];   // 32 KB
  __shared__ __align__(16) float  s_xh[256*16];    // [slot][row] 16 KB
  __shared__ __align__(16) float  s_d[256*16];     // [slot][row] 16 KB
  __shared__ unsigned int s_msk[16*8];             // [row][word] 512 B
  __shared__ float s_red[256];                     // [grp][row] 1 KB

  const int tid  = threadIdx.x;
  const int w    = tid >> 6;
  const int lane = tid & 63;
  const int l16  = lane & 15;
  const int g4   = lane >> 4;
  const int g8   = g4 * 8;

  const float wx0 = Wx[0], wx1 = Wx[1];

  // zero state
  unsigned int* zh = (unsigned int*)s_h;
  unsigned int* zc = (unsigned int*)s_c;
  #pragma unroll
  for (int it=0; it<32; ++it){ zh[tid + it*256] = 0u; zc[tid + it*256] = 0u; }

  // xh precompute: 4096 entries
  const float* xg = x + blockIdx.x * 4096;
  #pragma unroll
  for (int k=0; k<16; ++k){
    const int idx = tid + k*256;
    const int row = idx & 15, slot = idx >> 4;
    const int i = slot >> 4, t = slot & 15;
    const int c   = (i & 1) ? 15 - t : t;
    const int cpc = (i & 1) ? c + 1 : c - 1;
    const float xp = (t > 0) ? xg[row*256 + i*16 + cpc] : 0.f;
    const float xu = (i > 0) ? xg[row*256 + (i-1)*16 + c] : 0.f;
    s_xh[slot*16 + row] = (xp*wx0 + xu*wx1 + 1.f) * 0.5f;
  }
  // mask bits: x>0 at each slot's own cell
  if (tid < 128){
    const int row = tid >> 3, wd = tid & 7;
    unsigned int m = 0;
    for (int b=0; b<32; ++b){
      const int slot = wd*32 + b, i = slot >> 4, t = slot & 15;
      const int c = (i & 1) ? 15 - t : t;
      if (xg[row*256 + i*16 + c] > 0.f) m |= (1u << b);
    }
    s_msk[row*8 + wd] = m;
  }

  // weight fragments from prep table (identical addresses across blocks -> L2)
  const __bf16* tb = tbl + tid*176;
  bf16x8 G1f[4][2], G2f[4][2], bcf[4], fcB[2];
  #pragma unroll
  for (int g=0; g<4; ++g)
    #pragma unroll
    for (int s=0; s<2; ++s){
      G1f[g][s] = *(const bf16x8*)(tb + (g*2+s)*8);
      G2f[g][s] = *(const bf16x8*)(tb + 64 + (g*2+s)*8);
    }
  #pragma unroll
  for (int s=0; s<4; ++s) bcf[s] = *(const bf16x8*)(tb + 128 + s*8);
  #pragma unroll
  for (int s=0; s<2; ++s) fcB[s] = *(const bf16x8*)(tb + 160 + s*8);

  const float bd = bfc[0] - bfc[1];
  float base_[4], dvec_[4];
  #pragma unroll
  for (int g=0; g<4; ++g){
    const int cg = g*64 + w*16 + l16;
    const float sc = (g == 2) ? 2.f*L2E : L2E;
    base_[g] = (bih[cg] + bhh[cg] + Wih[cg*2+1]) * sc;
    dvec_[g] = (Wih[cg*2+0] - Wih[cg*2+1]) * sc;
  }
  const int colw = w*16 + l16;

  // per-lane LDS offsets (elements); col stride = 1024 els
  const int offA0 = l16*64 + ((     g8) ^ ((l16 & 7) << 3));
  const int offA1 = l16*64 + ((32 + g8) ^ ((l16 & 7) << 3));
  int stW[4];
  #pragma unroll
  for (int r=0;r<4;++r){
    const int row = g4*4 + r;
    stW[r] = row*64 + (colw ^ ((row & 7) << 3));
  }
  const float C2 = -2.f*L2E;

  __syncthreads();

  f32x4 accGu[4], aCu;

  for (int i=0; i<16; ++i){
    const int dir = i & 1;
    const int slot0 = i*16;

    // ---- row prologue: up-contribution for t=0 (+ wave3: d(slot0-1)) ----
    {
      const int b = (dir ? 15 : 0) << 10;
      bf16x8 ah0 = *(const bf16x8*)(s_h + b + offA0);
      bf16x8 ah1 = *(const bf16x8*)(s_h + b + offA1);
      bf16x8 qc0 = *(const bf16x8*)(s_c + b + offA0);
      bf16x8 qc1 = *(const bf16x8*)(s_c + b + offA1);
      const float4 xh4 = *(const float4*)(s_xh + slot0*16 + g4*4);
      #pragma unroll
      for (int g=0; g<4; ++g){
        accGu[g][0] = base_[g] + xh4.x * dvec_[g];
        accGu[g][1] = base_[g] + xh4.y * dvec_[g];
        accGu[g][2] = base_[g] + xh4.z * dvec_[g];
        accGu[g][3] = base_[g] + xh4.w * dvec_[g];
        accGu[g] = MFMA(ah0, G2f[g][0], accGu[g]);
        accGu[g] = MFMA(ah1, G2f[g][1], accGu[g]);
      }
      f32x4 z = {0.f,0.f,0.f,0.f};
      aCu = MFMA(qc0, bcf[2], z);
      aCu = MFMA(qc1, bcf[3], aCu);
      if (i > 0 && w == 3){                 // ((slot0-1)&3) == 3
        f32x4 fz = {bd,bd,bd,bd};
        fz = MFMA(ah0, fcB[0], fz);
        f32x4 aF = MFMA(ah1, fcB[1], fz);
        if (l16 == 0){
          #pragma unroll
          for (int r=0;r<4;++r) s_d[(slot0-1)*16 + g4*4 + r] = aF[r];
        }
      }
    }

    #pragma unroll 4
    for (int t=0; t<16; ++t){
      const int c    = dir ? 15 - t : t;
      const int slot = slot0 + t;
      const int cb   = c << 10;

      // ---- 1. issue ALL loads up-front (9 loads in flight) ----
      bf16x8 a0, a1, q0, q1;                // prev state (column c(t-1))
      if (t > 0){
        const int b = (dir ? c + 1 : c - 1) << 10;
        a0 = *(const bf16x8*)(s_h + b + offA0);
        a1 = *(const bf16x8*)(s_h + b + offA1);
        q0 = *(const bf16x8*)(s_c + b + offA0);
        q1 = *(const bf16x8*)(s_c + b + offA1);
      }
      bf16x8 au0, au1, cu0, cu1;            // up state for slot+1 (column c(t+1))
      float4 xh4n;
      if (t < 15){
        const int bu = (dir ? 14 - t : t + 1) << 10;
        au0 = *(const bf16x8*)(s_h + bu + offA0);
        au1 = *(const bf16x8*)(s_h + bu + offA1);
        cu0 = *(const bf16x8*)(s_c + bu + offA0);
        cu1 = *(const bf16x8*)(s_c + bu + offA1);
        xh4n = *(const float4*)(s_xh + (slot+1)*16 + g4*4);
      }

      // ---- 2. phase 1: gates/c_inter for cell t (waits on prev reads only) --
      f32x4 accG[4], aC;
      if (t > 0){
        #pragma unroll
        for (int g=0; g<4; ++g){
          accG[g] = MFMA(a0, G1f[g][0], accGu[g]);
          accG[g] = MFMA(a1, G1f[g][1], accG[g]);
        }
        aC = MFMA(q0, bcf[0], aCu);
        aC = MFMA(q1, bcf[1], aC);
        if (w == ((t - 1) & 3)){
          f32x4 fz = {bd,bd,bd,bd};
          fz = MFMA(a0, fcB[0], fz);
          f32x4 aF = MFMA(a1, fcB[1], fz);
          if (l16 == 0){
            #pragma unroll
            for (int r=0;r<4;++r) s_d[(slot-1)*16 + g4*4 + r] = aF[r];
          }
        }
      } else {
        #pragma unroll
        for (int g=0; g<4; ++g) accG[g] = accGu[g];
        aC = aCu;
      }

      // ---- 3. epilogue trans block (up-read latency hides under this) ----
      // A=2^-i', F=2^-f', B=2^-g'', O=2^-o'
      // cn = [cI*(1+A)(1+B) + (1-B)(1+F)] / [(1+F)(1+A)(1+B)]
      // hn = (1-E)/[(1+O)(1+E)],  E = 2^(-2*l2e*cn)
      float hnv[4], cnv[4];
      #pragma unroll
      for (int r=0;r<4;++r){
        const float A = exp2f(-accG[0][r]);
        const float F = exp2f(-accG[1][r]);
        const float B = exp2f(-accG[2][r]);
        const float O = exp2f(-accG[3][r]);
        const float a1_ = 1.f + A, f1 = 1.f + F, b1 = 1.f + B, o1 = 1.f + O;
        const float pab = a1_ * b1;
        const float num = fmaf(1.f - B, f1, aC[r] * pab);
        const float cn  = num * rcp_(pab * f1);
        const float E   = exp2f(C2 * cn);
        const float hn  = (1.f - E) * rcp_(o1 * (1.f + E));
        hnv[r] = hn; cnv[r] = cn;
      }

      // ---- 4. state writes (issue as soon as values ready) ----
      #pragma unroll
      for (int r=0;r<4;++r){
        s_h[cb + stW[r]] = (__bf16)hnv[r];
        s_c[cb + stW[r]] = (__bf16)cnv[r];
      }

      // ---- 5. prefetch MFMAs for slot+1 (reads landed long ago) ----
      if (t < 15){
        #pragma unroll
        for (int g=0; g<4; ++g){
          accGu[g][0] = base_[g] + xh4n.x * dvec_[g];
          accGu[g][1] = base_[g] + xh4n.y * dvec_[g];
          accGu[g][2] = base_[g] + xh4n.z * dvec_[g];
          accGu[g][3] = base_[g] + xh4n.w * dvec_[g];
          accGu[g] = MFMA(au0, G2f[g][0], accGu[g]);
          accGu[g] = MFMA(au1, G2f[g][1], accGu[g]);
        }
        f32x4 z = {0.f,0.f,0.f,0.f};
        aCu = MFMA(cu0, bcf[2], z);
        aCu = MFMA(cu1, bcf[3], aCu);
      }

      __syncthreads();
    }
  }

  // d(255): slot 255 ends at column 0
  if (w == 3){
    bf16x8 a0 = *(const bf16x8*)(s_h + offA0);
    bf16x8 a1 = *(const bf16x8*)(s_h + offA1);
    f32x4 fz = {bd,bd,bd,bd};
    fz = MFMA(a0, fcB[0], fz);
    f32x4 aF = MFMA(a1, fcB[1], fz);
    if (l16 == 0){
      #pragma unroll
      for (int r=0;r<4;++r) s_d[255*16 + g4*4 + r] = aF[r];
    }
  }
  __syncthreads();

  // ---------- end phase: all 4096 log-softmax terms in parallel ----------
  {
    const int row = tid & 15, grp = tid >> 4;   // 16 groups x 16 slots
    float lpp = 0.f;
    #pragma unroll
    for (int e=0; e<16; ++e){
      const int slot = grp*16 + e;
      const float d = s_d[slot*16 + row];
      const int msk = (s_msk[row*8 + (slot >> 5)] >> (slot & 31)) & 1;
      const float zz = msk ? -d : d;
      lpp -= __logf(1.f + __expf(zz));
    }
    s_red[grp*16 + row] = lpp;
  }
  __syncthreads();
  if (tid < 16){
    const int row = tid;
    float lp = 0.f;
    #pragma unroll
    for (int g=0; g<16; ++g) lp += s_red[g*16 + row];
    int aa = 0;
    #pragma unroll
    for (int wd=0; wd<8; ++wd) aa += __popc(s_msk[row*8 + wd]);
    const int m255 = (s_msk[row*8 + 7] >> 31) & 1;
    if (aa == 1 && m255){
      const float d = s_d[255*16 + row];
      lp += __logf(1.f + __expf(-d));   // remove contrib (factor = 1 - mask)
    }
    out[blockIdx.x*16 + row] = lp;
  }
}

extern "C" void kernel_launch(void* const* d_in, const int* in_sizes, int n_in,
                              void* d_out, int out_size, void* d_ws, size_t ws_size,
                              hipStream_t stream) {
  const float* x   = (const float*)d_in[0];
  const float* Wx  = (const float*)d_in[1];
  const float* Wh  = (const float*)d_in[2];
  const float* Wh2 = (const float*)d_in[3];
  const float* Wih = (const float*)d_in[4];
  const float* Whh = (const float*)d_in[5];
  const float* bih = (const float*)d_in[6];
  const float* bhh = (const float*)d_in[7];
  const float* Wfc = (const float*)d_in[8];
  const float* bfc = (const float*)d_in[9];
  float* out = (float*)d_out;
  __bf16* tbl = (__bf16*)d_ws;   // 256*176*2 = 90112 B

  prep_kernel<<<dim3(176), dim3(256), 0, stream>>>(Wh, Wh2, Whh, Wfc, tbl);
  lstm2d_kernel<<<dim3(256), dim3(256), 0, stream>>>(
      x, Wx, Wih, bih, bhh, bfc, tbl, out);
}